// Round 2
// baseline (1356.640 us; speedup 1.0000x reference)
//
#include <hip/hip_runtime.h>

#define NB 8
#define DM 256
#define FD 96
#define PPB 128   // positions per block in einsum kernel

__device__ __forceinline__ float clamp01(float x) { return fminf(fmaxf(x, 0.0f), 1.0f); }

// ---------------------------------------------------------------------------
// Kernel A: per-position sim (1 thread/pos), h/W written via LDS transpose so
// every global store instruction covers full 128B lines (no write amplification).
// ---------------------------------------------------------------------------
__global__ __launch_bounds__(256, 2) void bio_sim_kernel(
    const int* __restrict__ bits,
    const float* __restrict__ stim_in,
    const float* __restrict__ Winit,
    const int* __restrict__ steps_ptr,
    float* __restrict__ out_h,
    float* __restrict__ out_W,
    int npos)
{
    const int pos = blockIdx.x * blockDim.x + threadIdx.x;
    const int steps = steps_ptr[0];

    float h[NB][4];
    float W[NB][NB];

    // ---- decode bits -> h: pairs (2b) -> {0,1/3,2/3,1}
    const int4* bp = reinterpret_cast<const int4*>(bits + (size_t)pos * 64);
    #pragma unroll
    for (int b = 0; b < NB; ++b) {
        int4 lo = bp[2 * b + 0];
        int4 hi = bp[2 * b + 1];
        h[b][0] = (float)(lo.x * 2 + lo.y) / 3.0f;
        h[b][1] = (float)(lo.z * 2 + lo.w) / 3.0f;
        h[b][2] = (float)(hi.x * 2 + hi.y) / 3.0f;
        h[b][3] = (float)(hi.z * 2 + hi.w) / 3.0f;
    }

    // ---- W_init, zero diagonal (diag stays 0 forever)
    const float4* wp = reinterpret_cast<const float4*>(Winit + (size_t)pos * 64);
    #pragma unroll
    for (int i = 0; i < NB; ++i) {
        float4 a = wp[2 * i + 0];
        float4 b = wp[2 * i + 1];
        W[i][0] = a.x; W[i][1] = a.y; W[i][2] = a.z; W[i][3] = a.w;
        W[i][4] = b.x; W[i][5] = b.y; W[i][6] = b.z; W[i][7] = b.w;
        W[i][i] = 0.0f;
    }

    const float stim = stim_in[pos];

    for (int st = 0; st < steps; ++st) {
        float nb[NB][4];
        #pragma unroll
        for (int i = 0; i < NB; ++i) {
            float s0 = 0.f, s1 = 0.f, s2 = 0.f, s3 = 0.f, tw = 0.f;
            #pragma unroll
            for (int j = 0; j < NB; ++j) {
                float w = W[i][j];
                s0 += w * h[j][0];
                s1 += w * h[j][1];
                s2 += w * h[j][2];
                s3 += w * h[j][3];
                tw += w;
            }
            float inv = 1.0f / (tw + 1e-8f);
            nb[i][0] = s0 * inv; nb[i][1] = s1 * inv;
            nb[i][2] = s2 * inv; nb[i][3] = s3 * inv;
        }
        #pragma unroll
        for (int i = 0; i < NB; ++i) {
            float E = h[i][0], P = h[i][1], G = h[i][2], L = h[i][3];
            float En = nb[i][0], Pn = nb[i][1], Gn = nb[i][2], Ln = nb[i][3];
            float E_new = clamp01(E + 0.3f * stim - 0.4f * P - 0.2f * G);
            float P_new = clamp01(P + 0.5f * stim + 0.3f * (Pn - P) - 0.2f * E);
            float G_new = clamp01(G + 0.4f * E * (1.0f - P) + 0.2f * (Gn - G) - 0.3f * P);
            float good  = 0.5f * En + 0.5f * Gn;
            float L_new = clamp01(L + 0.4f * good + 0.3f * (Ln - L) - 0.3f * P);
            h[i][0] = E_new; h[i][1] = P_new; h[i][2] = G_new; h[i][3] = L_new;
        }
        #pragma unroll
        for (int i = 0; i < NB; ++i) {
            #pragma unroll
            for (int j = i + 1; j < NB; ++j) {
                float d0 = h[i][0] - h[j][0];
                float d1 = h[i][1] - h[j][1];
                float d2 = h[i][2] - h[j][2];
                float d3 = h[i][3] - h[j][3];
                float q = d0 * d0 + d1 * d1 + d2 * d2 + d3 * d3;
                float dist = (q > 0.0f) ? sqrtf(q) : 0.0f;
                float inc = 0.1f * (0.5f * (h[i][3] + h[j][3])) * dist;
                W[i][j] = clamp01(W[i][j] + inc - 0.05f * W[i][j]);
                W[j][i] = clamp01(W[j][i] + inc - 0.05f * W[j][i]);
            }
        }
    }

    // ---- coalesced output via per-wave LDS transpose (XOR-swizzled, conflict-free)
    __shared__ float xpose[4][4096];   // 64 KB: per-wave 16 KB region
    const int w = threadIdx.x >> 6;
    const int l = threadIdx.x & 63;
    float* buf = xpose[w];
    const int waveBase = blockIdx.x * 256 + w * 64;   // first pos of this wave

    // W: lane l = pos, 64 floats row-major
    #pragma unroll
    for (int f = 0; f < 64; ++f)
        buf[l * 64 + (f ^ (l & 31))] = W[f >> 3][f & 7];
    __syncthreads();
    {
        float* dst = out_W + (size_t)waveBase * 64;
        #pragma unroll
        for (int i = 0; i < 64; ++i)
            dst[i * 64 + l] = buf[i * 64 + (l ^ (i & 31))];   // 256B contiguous/inst
    }
    __syncthreads();
    // h: 32 floats per pos (reuse first 8 KB of wave region)
    #pragma unroll
    for (int f = 0; f < 32; ++f)
        buf[l * 32 + (f ^ (l & 31))] = h[f >> 2][f & 3];
    __syncthreads();
    {
        float* dst = out_h + (size_t)waveBase * 32;
        #pragma unroll
        for (int i = 0; i < 32; ++i) {
            int p = i * 2 + (l >> 5), f = l & 31;
            dst[i * 64 + l] = buf[p * 32 + (f ^ (p & 31))];
        }
    }
}

// ---------------------------------------------------------------------------
// Kernel B: emb[p][d] = lin_b[d] + sum_f phys[p][f]*lin_w[d][f]
// thread <-> d (lin_w row in 96 VGPRs, reused over PPB positions),
// phys wave-uniform -> scalar loads, stores wave-coalesced (256B contiguous).
// ---------------------------------------------------------------------------
__global__ __launch_bounds__(256, 4) void einsum_kernel(
    const float* __restrict__ hsrc,
    const float* __restrict__ wsrc,
    const float* __restrict__ lin_w,
    const float* __restrict__ lin_b,
    float* __restrict__ out_emb)
{
    const int d  = threadIdx.x;          // 0..255
    const int p0 = blockIdx.x * PPB;

    float lw[FD];
    const float4* lwp = reinterpret_cast<const float4*>(lin_w + (size_t)d * FD);
    #pragma unroll
    for (int q = 0; q < FD / 4; ++q) {
        float4 v = lwp[q];
        lw[q * 4 + 0] = v.x; lw[q * 4 + 1] = v.y;
        lw[q * 4 + 2] = v.z; lw[q * 4 + 3] = v.w;
    }
    const float bias = lin_b[d];

    for (int pp = 0; pp < PPB; pp += 2) {
        const int p = p0 + pp;
        const float* __restrict__ h0 = hsrc + (size_t)p * 32;
        const float* __restrict__ h1 = h0 + 32;
        const float* __restrict__ w0 = wsrc + (size_t)p * 64;
        const float* __restrict__ w1 = w0 + 64;
        float a0 = bias, a1 = bias;
        #pragma unroll
        for (int f = 0; f < 32; ++f) { a0 += lw[f] * h0[f]; a1 += lw[f] * h1[f]; }
        #pragma unroll
        for (int f = 0; f < 64; ++f) { a0 += lw[32 + f] * w0[f]; a1 += lw[32 + f] * w1[f]; }
        out_emb[(size_t)p * DM + d]       = a0;
        out_emb[(size_t)(p + 1) * DM + d] = a1;
    }
}

extern "C" void kernel_launch(void* const* d_in, const int* in_sizes, int n_in,
                              void* d_out, int out_size, void* d_ws, size_t ws_size,
                              hipStream_t stream) {
    const int*   bits  = (const int*)d_in[0];
    const float* stim  = (const float*)d_in[1];
    const float* Winit = (const float*)d_in[2];
    const float* lin_w = (const float*)d_in[3];
    const float* lin_b = (const float*)d_in[4];
    const int*   steps = (const int*)d_in[5];

    const int npos = in_sizes[1];   // B*S = 131072

    float* out_emb = (float*)d_out;
    float* out_h   = out_emb + (size_t)npos * DM;
    float* out_W   = out_h + (size_t)npos * 32;

    hipLaunchKernelGGL(bio_sim_kernel, dim3(npos / 256), dim3(256), 0, stream,
                       bits, stim, Winit, steps, out_h, out_W, npos);
    hipLaunchKernelGGL(einsum_kernel, dim3(npos / PPB), dim3(256), 0, stream,
                       out_h, out_W, lin_w, lin_b, out_emb);
}

// Round 3
// 273.643 us; speedup vs baseline: 4.9577x; 4.9577x over previous
//
#include <hip/hip_runtime.h>

#define NB 8
#define DM 256
#define FD 96

__device__ __forceinline__ float clamp01(float x) { return fminf(fmaxf(x, 0.0f), 1.0f); }

// ---------------------------------------------------------------------------
// Kernel A: per-position sim (1 thread/pos), h/W written via per-wave LDS
// transpose so every global store instruction covers full 128B lines.
// ---------------------------------------------------------------------------
__global__ __launch_bounds__(256, 2) void bio_sim_kernel(
    const int* __restrict__ bits,
    const float* __restrict__ stim_in,
    const float* __restrict__ Winit,
    const int* __restrict__ steps_ptr,
    float* __restrict__ out_h,
    float* __restrict__ out_W,
    int npos)
{
    const int pos = blockIdx.x * blockDim.x + threadIdx.x;
    const int steps = steps_ptr[0];

    float h[NB][4];
    float W[NB][NB];

    // ---- decode bits -> h: pairs (2b) -> {0,1/3,2/3,1}
    const int4* bp = reinterpret_cast<const int4*>(bits + (size_t)pos * 64);
    #pragma unroll
    for (int b = 0; b < NB; ++b) {
        int4 lo = bp[2 * b + 0];
        int4 hi = bp[2 * b + 1];
        h[b][0] = (float)(lo.x * 2 + lo.y) / 3.0f;
        h[b][1] = (float)(lo.z * 2 + lo.w) / 3.0f;
        h[b][2] = (float)(hi.x * 2 + hi.y) / 3.0f;
        h[b][3] = (float)(hi.z * 2 + hi.w) / 3.0f;
    }

    // ---- W_init, zero diagonal (diag stays 0 forever)
    const float4* wp = reinterpret_cast<const float4*>(Winit + (size_t)pos * 64);
    #pragma unroll
    for (int i = 0; i < NB; ++i) {
        float4 a = wp[2 * i + 0];
        float4 b = wp[2 * i + 1];
        W[i][0] = a.x; W[i][1] = a.y; W[i][2] = a.z; W[i][3] = a.w;
        W[i][4] = b.x; W[i][5] = b.y; W[i][6] = b.z; W[i][7] = b.w;
        W[i][i] = 0.0f;
    }

    const float stim = stim_in[pos];

    for (int st = 0; st < steps; ++st) {
        float nb[NB][4];
        #pragma unroll
        for (int i = 0; i < NB; ++i) {
            float s0 = 0.f, s1 = 0.f, s2 = 0.f, s3 = 0.f, tw = 0.f;
            #pragma unroll
            for (int j = 0; j < NB; ++j) {
                float w = W[i][j];
                s0 += w * h[j][0];
                s1 += w * h[j][1];
                s2 += w * h[j][2];
                s3 += w * h[j][3];
                tw += w;
            }
            float inv = 1.0f / (tw + 1e-8f);
            nb[i][0] = s0 * inv; nb[i][1] = s1 * inv;
            nb[i][2] = s2 * inv; nb[i][3] = s3 * inv;
        }
        #pragma unroll
        for (int i = 0; i < NB; ++i) {
            float E = h[i][0], P = h[i][1], G = h[i][2], L = h[i][3];
            float En = nb[i][0], Pn = nb[i][1], Gn = nb[i][2], Ln = nb[i][3];
            float E_new = clamp01(E + 0.3f * stim - 0.4f * P - 0.2f * G);
            float P_new = clamp01(P + 0.5f * stim + 0.3f * (Pn - P) - 0.2f * E);
            float G_new = clamp01(G + 0.4f * E * (1.0f - P) + 0.2f * (Gn - G) - 0.3f * P);
            float good  = 0.5f * En + 0.5f * Gn;
            float L_new = clamp01(L + 0.4f * good + 0.3f * (Ln - L) - 0.3f * P);
            h[i][0] = E_new; h[i][1] = P_new; h[i][2] = G_new; h[i][3] = L_new;
        }
        #pragma unroll
        for (int i = 0; i < NB; ++i) {
            #pragma unroll
            for (int j = i + 1; j < NB; ++j) {
                float d0 = h[i][0] - h[j][0];
                float d1 = h[i][1] - h[j][1];
                float d2 = h[i][2] - h[j][2];
                float d3 = h[i][3] - h[j][3];
                float q = d0 * d0 + d1 * d1 + d2 * d2 + d3 * d3;
                float dist = (q > 0.0f) ? sqrtf(q) : 0.0f;
                float inc = 0.1f * (0.5f * (h[i][3] + h[j][3])) * dist;
                W[i][j] = clamp01(W[i][j] + inc - 0.05f * W[i][j]);
                W[j][i] = clamp01(W[j][i] + inc - 0.05f * W[j][i]);
            }
        }
    }

    // ---- coalesced output via per-wave LDS transpose (XOR-swizzled)
    __shared__ float xpose[4][4096];   // 64 KB: per-wave 16 KB region
    const int w = threadIdx.x >> 6;
    const int l = threadIdx.x & 63;
    float* buf = xpose[w];
    const int waveBase = blockIdx.x * 256 + w * 64;

    #pragma unroll
    for (int f = 0; f < 64; ++f)
        buf[l * 64 + (f ^ (l & 31))] = W[f >> 3][f & 7];
    __syncthreads();
    {
        float* dst = out_W + (size_t)waveBase * 64;
        #pragma unroll
        for (int i = 0; i < 64; ++i)
            dst[i * 64 + l] = buf[i * 64 + (l ^ (i & 31))];   // 256B contiguous/inst
    }
    __syncthreads();
    #pragma unroll
    for (int f = 0; f < 32; ++f)
        buf[l * 32 + (f ^ (l & 31))] = h[f >> 2][f & 3];
    __syncthreads();
    {
        float* dst = out_h + (size_t)waveBase * 32;
        #pragma unroll
        for (int i = 0; i < 32; ++i) {
            int p = i * 2 + (l >> 5), f = l & 31;
            dst[i * 64 + l] = buf[p * 32 + (f ^ (p & 31))];
        }
    }
}

// ---------------------------------------------------------------------------
// Kernel B: emb[p][d] = lin_b[d] + sum_f phys[p][f]*lin_w[d][f]
// thread <-> position: phys[96] in VGPRs (static indexing, no spill at 256-cap),
// lin_w/lin_b indices wave-uniform -> s_load into SGPRs (zero VGPR cost),
// emb staged per-wave in XOR-swizzled LDS and flushed 256B-contiguous
// (each store = 2 full 128B lines -> no partial-line RMW).
// ---------------------------------------------------------------------------
__global__ __launch_bounds__(256, 2) void einsum_kernel(
    const float* __restrict__ hsrc,
    const float* __restrict__ wsrc,
    const float* __restrict__ lin_w,
    const float* __restrict__ lin_b,
    float* __restrict__ out_emb)
{
    __shared__ float xb[4][4096];      // 64 KB: per-wave 16 KB
    const int tid = threadIdx.x;
    const int w = tid >> 6, l = tid & 63;
    const int pos = blockIdx.x * 256 + tid;

    float phys[FD];
    {
        const float4* hp = reinterpret_cast<const float4*>(hsrc + (size_t)pos * 32);
        #pragma unroll
        for (int q = 0; q < 8; ++q) {
            float4 v = hp[q];
            phys[q * 4 + 0] = v.x; phys[q * 4 + 1] = v.y;
            phys[q * 4 + 2] = v.z; phys[q * 4 + 3] = v.w;
        }
        const float4* wp = reinterpret_cast<const float4*>(wsrc + (size_t)pos * 64);
        #pragma unroll
        for (int q = 0; q < 16; ++q) {
            float4 v = wp[q];
            phys[32 + q * 4 + 0] = v.x; phys[32 + q * 4 + 1] = v.y;
            phys[32 + q * 4 + 2] = v.z; phys[32 + q * 4 + 3] = v.w;
        }
    }

    float* buf = xb[w];
    const int waveBase = blockIdx.x * 256 + w * 64;

    for (int d0 = 0; d0 < DM; d0 += 64) {          // 4 d-chunks
        #pragma unroll 1
        for (int t8 = 0; t8 < 64; t8 += 8) {       // 8 rows of lin_w per body
            float acc[8];
            #pragma unroll
            for (int t = 0; t < 8; ++t) {
                const float* lw = lin_w + (size_t)(d0 + t8 + t) * FD;  // uniform -> s_load
                float a = lin_b[d0 + t8 + t];
                #pragma unroll
                for (int f = 0; f < FD; ++f)
                    a = fmaf(phys[f], lw[f], a);
                acc[t] = a;
            }
            #pragma unroll
            for (int t = 0; t < 8; ++t)
                buf[l * 64 + ((t8 + t) ^ (l & 31))] = acc[t];
        }
        // flush chunk: 64 rows x 256B contiguous (2 full lines per store inst)
        #pragma unroll 8
        for (int i = 0; i < 64; ++i)
            out_emb[(size_t)(waveBase + i) * DM + d0 + l] = buf[i * 64 + (l ^ (i & 31))];
    }
}

extern "C" void kernel_launch(void* const* d_in, const int* in_sizes, int n_in,
                              void* d_out, int out_size, void* d_ws, size_t ws_size,
                              hipStream_t stream) {
    const int*   bits  = (const int*)d_in[0];
    const float* stim  = (const float*)d_in[1];
    const float* Winit = (const float*)d_in[2];
    const float* lin_w = (const float*)d_in[3];
    const float* lin_b = (const float*)d_in[4];
    const int*   steps = (const int*)d_in[5];

    const int npos = in_sizes[1];   // B*S = 131072

    float* out_emb = (float*)d_out;
    float* out_h   = out_emb + (size_t)npos * DM;
    float* out_W   = out_h + (size_t)npos * 32;

    hipLaunchKernelGGL(bio_sim_kernel, dim3(npos / 256), dim3(256), 0, stream,
                       bits, stim, Winit, steps, out_h, out_W, npos);
    hipLaunchKernelGGL(einsum_kernel, dim3(npos / 256), dim3(256), 0, stream,
                       out_h, out_W, lin_w, lin_b, out_emb);
}

// Round 4
// 122.824 us; speedup vs baseline: 11.0454x; 2.2279x over previous
//
#include <hip/hip_runtime.h>

#define NB 8
#define DM 256
#define FD 96

using half8 = _Float16 __attribute__((ext_vector_type(8)));
using f32x4 = float __attribute__((ext_vector_type(4)));

__device__ __forceinline__ float clamp01(float x) { return fminf(fmaxf(x, 0.0f), 1.0f); }

// ---------------------------------------------------------------------------
// Kernel A: per-position sim (1 thread/pos), h/W written via per-wave LDS
// transpose so every global store instruction covers full 128B lines.
// ---------------------------------------------------------------------------
__global__ __launch_bounds__(256, 2) void bio_sim_kernel(
    const int* __restrict__ bits,
    const float* __restrict__ stim_in,
    const float* __restrict__ Winit,
    const int* __restrict__ steps_ptr,
    float* __restrict__ out_h,
    float* __restrict__ out_W,
    int npos)
{
    const int pos = blockIdx.x * blockDim.x + threadIdx.x;
    const int steps = steps_ptr[0];

    float h[NB][4];
    float W[NB][NB];

    const int4* bp = reinterpret_cast<const int4*>(bits + (size_t)pos * 64);
    #pragma unroll
    for (int b = 0; b < NB; ++b) {
        int4 lo = bp[2 * b + 0];
        int4 hi = bp[2 * b + 1];
        h[b][0] = (float)(lo.x * 2 + lo.y) / 3.0f;
        h[b][1] = (float)(lo.z * 2 + lo.w) / 3.0f;
        h[b][2] = (float)(hi.x * 2 + hi.y) / 3.0f;
        h[b][3] = (float)(hi.z * 2 + hi.w) / 3.0f;
    }

    const float4* wp = reinterpret_cast<const float4*>(Winit + (size_t)pos * 64);
    #pragma unroll
    for (int i = 0; i < NB; ++i) {
        float4 a = wp[2 * i + 0];
        float4 b = wp[2 * i + 1];
        W[i][0] = a.x; W[i][1] = a.y; W[i][2] = a.z; W[i][3] = a.w;
        W[i][4] = b.x; W[i][5] = b.y; W[i][6] = b.z; W[i][7] = b.w;
        W[i][i] = 0.0f;
    }

    const float stim = stim_in[pos];

    for (int st = 0; st < steps; ++st) {
        float nb[NB][4];
        #pragma unroll
        for (int i = 0; i < NB; ++i) {
            float s0 = 0.f, s1 = 0.f, s2 = 0.f, s3 = 0.f, tw = 0.f;
            #pragma unroll
            for (int j = 0; j < NB; ++j) {
                float w = W[i][j];
                s0 += w * h[j][0];
                s1 += w * h[j][1];
                s2 += w * h[j][2];
                s3 += w * h[j][3];
                tw += w;
            }
            float inv = 1.0f / (tw + 1e-8f);
            nb[i][0] = s0 * inv; nb[i][1] = s1 * inv;
            nb[i][2] = s2 * inv; nb[i][3] = s3 * inv;
        }
        #pragma unroll
        for (int i = 0; i < NB; ++i) {
            float E = h[i][0], P = h[i][1], G = h[i][2], L = h[i][3];
            float En = nb[i][0], Pn = nb[i][1], Gn = nb[i][2], Ln = nb[i][3];
            float E_new = clamp01(E + 0.3f * stim - 0.4f * P - 0.2f * G);
            float P_new = clamp01(P + 0.5f * stim + 0.3f * (Pn - P) - 0.2f * E);
            float G_new = clamp01(G + 0.4f * E * (1.0f - P) + 0.2f * (Gn - G) - 0.3f * P);
            float good  = 0.5f * En + 0.5f * Gn;
            float L_new = clamp01(L + 0.4f * good + 0.3f * (Ln - L) - 0.3f * P);
            h[i][0] = E_new; h[i][1] = P_new; h[i][2] = G_new; h[i][3] = L_new;
        }
        #pragma unroll
        for (int i = 0; i < NB; ++i) {
            #pragma unroll
            for (int j = i + 1; j < NB; ++j) {
                float d0 = h[i][0] - h[j][0];
                float d1 = h[i][1] - h[j][1];
                float d2 = h[i][2] - h[j][2];
                float d3 = h[i][3] - h[j][3];
                float q = d0 * d0 + d1 * d1 + d2 * d2 + d3 * d3;
                float dist = (q > 0.0f) ? sqrtf(q) : 0.0f;
                float inc = 0.1f * (0.5f * (h[i][3] + h[j][3])) * dist;
                W[i][j] = clamp01(W[i][j] + inc - 0.05f * W[i][j]);
                W[j][i] = clamp01(W[j][i] + inc - 0.05f * W[j][i]);
            }
        }
    }

    __shared__ float xpose[4][4096];   // 64 KB: per-wave 16 KB region
    const int w = threadIdx.x >> 6;
    const int l = threadIdx.x & 63;
    float* buf = xpose[w];
    const int waveBase = blockIdx.x * 256 + w * 64;

    #pragma unroll
    for (int f = 0; f < 64; ++f)
        buf[l * 64 + (f ^ (l & 31))] = W[f >> 3][f & 7];
    __syncthreads();
    {
        float* dst = out_W + (size_t)waveBase * 64;
        #pragma unroll
        for (int i = 0; i < 64; ++i)
            dst[i * 64 + l] = buf[i * 64 + (l ^ (i & 31))];
    }
    __syncthreads();
    #pragma unroll
    for (int f = 0; f < 32; ++f)
        buf[l * 32 + (f ^ (l & 31))] = h[f >> 2][f & 3];
    __syncthreads();
    {
        float* dst = out_h + (size_t)waveBase * 32;
        #pragma unroll
        for (int i = 0; i < 32; ++i) {
            int p = i * 2 + (l >> 5), f = l & 31;
            dst[i * 64 + l] = buf[p * 32 + (f ^ (p & 31))];
        }
    }
}

// ---------------------------------------------------------------------------
// Kernel B: emb = phys @ lin_w^T + lin_b  via f16 MFMA (fp32 accumulate).
// Block = 64 positions x full N=256. A (phys) and B (lin_w^T) staged in LDS
// pre-arranged in 16x16x32 fragment order -> each operand = 1 ds_read_b128.
// Frag map (m162/m89): elem j <-> k = 4*(l>>4)+(j&3)+16*(j>>2); A row / B col
// = l&15; C/D: row = 4*(l>>4)+reg, col = l&15. C flushed via padded LDS
// transpose -> 1KB-contiguous full-line stores.
// ---------------------------------------------------------------------------
__global__ __launch_bounds__(256, 2) void einsum_mfma_kernel(
    const float* __restrict__ hsrc,
    const float* __restrict__ wsrc,
    const float* __restrict__ lin_w,
    const float* __restrict__ lin_b,
    float* __restrict__ out_emb)
{
    __shared__ char smem[66560];
    _Float16* Bfr = reinterpret_cast<_Float16*>(smem);          // [3][16][64][8]
    _Float16* Afr = reinterpret_cast<_Float16*>(smem + 49152);  // [3][4][64][8]
    float*    Cbuf = reinterpret_cast<float*>(smem);            // [64][260] overlay

    const int tid = threadIdx.x;
    const int w = tid >> 6, l = tid & 63;
    const int pos0 = blockIdx.x * 64;

    const float4 biasv = reinterpret_cast<const float4*>(lin_b)[l];  // cols 4l..4l+3

    // ---- stage B = lin_w^T as f16 fragments (lin_w is [256][96] row-major)
    #pragma unroll
    for (int i = 0; i < 12; ++i) {
        const int fb = i * 256 + tid;                 // 0..3071
        const int ks = fb >> 10, nb = (fb >> 6) & 15, ll = fb & 63;
        const float* lwrow = lin_w + (size_t)(nb * 16 + (ll & 15)) * FD
                                   + (ks * 32 + 4 * (ll >> 4));
        float4 lo = *reinterpret_cast<const float4*>(lwrow);
        float4 hi = *reinterpret_cast<const float4*>(lwrow + 16);
        half8 v;
        v[0] = (_Float16)lo.x; v[1] = (_Float16)lo.y; v[2] = (_Float16)lo.z; v[3] = (_Float16)lo.w;
        v[4] = (_Float16)hi.x; v[5] = (_Float16)hi.y; v[6] = (_Float16)hi.z; v[7] = (_Float16)hi.w;
        *reinterpret_cast<half8*>(Bfr + (size_t)fb * 8) = v;
    }

    // ---- stage A = phys (h:0..31, W:32..95) as f16 fragments; mb = w
    #pragma unroll
    for (int ks = 0; ks < 3; ++ks) {
        const int row = w * 16 + (l & 15);
        const int pos = pos0 + row;
        const int kbase = ks * 32 + 4 * (l >> 4);
        const float* src = (ks == 0) ? (hsrc + (size_t)pos * 32 + kbase)
                                     : (wsrc + (size_t)pos * 64 + (kbase - 32));
        float4 lo = *reinterpret_cast<const float4*>(src);
        float4 hi = *reinterpret_cast<const float4*>(src + 16);
        half8 v;
        v[0] = (_Float16)lo.x; v[1] = (_Float16)lo.y; v[2] = (_Float16)lo.z; v[3] = (_Float16)lo.w;
        v[4] = (_Float16)hi.x; v[5] = (_Float16)hi.y; v[6] = (_Float16)hi.z; v[7] = (_Float16)hi.w;
        *reinterpret_cast<half8*>(Afr + (size_t)(ks * 256 + tid) * 8) = v;
    }
    __syncthreads();

    // ---- MFMA: 3 K-steps x 16 N-frags, wave w owns rows w*16..w*16+15
    f32x4 acc[16];
    #pragma unroll
    for (int nb = 0; nb < 16; ++nb) acc[nb] = (f32x4){0.f, 0.f, 0.f, 0.f};
    #pragma unroll
    for (int ks = 0; ks < 3; ++ks) {
        half8 a = *reinterpret_cast<const half8*>(Afr + (size_t)((ks * 4 + w) * 64 + l) * 8);
        #pragma unroll
        for (int nb = 0; nb < 16; ++nb) {
            half8 b = *reinterpret_cast<const half8*>(Bfr + (size_t)((ks * 16 + nb) * 64 + l) * 8);
            acc[nb] = __builtin_amdgcn_mfma_f32_16x16x32_f16(a, b, acc[nb], 0, 0, 0);
        }
    }
    __syncthreads();   // all frag ds_reads consumed before Cbuf overlay

    // ---- acc -> Cbuf (padded stride 260 -> <=2-way bank alias, free)
    #pragma unroll
    for (int nb = 0; nb < 16; ++nb) {
        #pragma unroll
        for (int r = 0; r < 4; ++r) {
            const int row = w * 16 + 4 * (l >> 4) + r;
            Cbuf[row * 260 + nb * 16 + (l & 15)] = acc[nb][r];
        }
    }
    __syncthreads();

    // ---- flush: each wave stores one full 1KB row per rep + bias
    #pragma unroll
    for (int rep = 0; rep < 16; ++rep) {
        const int row = rep * 4 + w;
        float4 v = *reinterpret_cast<const float4*>(Cbuf + row * 260 + l * 4);
        v.x += biasv.x; v.y += biasv.y; v.z += biasv.z; v.w += biasv.w;
        *reinterpret_cast<float4*>(out_emb + (size_t)(pos0 + row) * DM + l * 4) = v;
    }
}

extern "C" void kernel_launch(void* const* d_in, const int* in_sizes, int n_in,
                              void* d_out, int out_size, void* d_ws, size_t ws_size,
                              hipStream_t stream) {
    const int*   bits  = (const int*)d_in[0];
    const float* stim  = (const float*)d_in[1];
    const float* Winit = (const float*)d_in[2];
    const float* lin_w = (const float*)d_in[3];
    const float* lin_b = (const float*)d_in[4];
    const int*   steps = (const int*)d_in[5];

    const int npos = in_sizes[1];   // B*S = 131072

    float* out_emb = (float*)d_out;
    float* out_h   = out_emb + (size_t)npos * DM;
    float* out_W   = out_h + (size_t)npos * 32;

    hipLaunchKernelGGL(bio_sim_kernel, dim3(npos / 256), dim3(256), 0, stream,
                       bits, stim, Winit, steps, out_h, out_W, npos);
    hipLaunchKernelGGL(einsum_mfma_kernel, dim3(npos / 64), dim3(256), 0, stream,
                       out_h, out_W, lin_w, lin_b, out_emb);
}